// Round 1
// baseline (2563.583 us; speedup 1.0000x reference)
//
#include <hip/hip_runtime.h>

#define D_MODEL 4096
#define HID     10922
#define HIDP    11008   // padded to multiple of 128
#define MTOK    4096
#define QMAXF   127.0f

typedef _Float16 half8  __attribute__((ext_vector_type(8)));
typedef _Float16 half4v __attribute__((ext_vector_type(4)));
typedef float    floatx4 __attribute__((ext_vector_type(4)));

// ---------------- async global->LDS (16B per lane, wave-uniform LDS base) ----
__device__ __forceinline__ void gl_lds16(const void* g, void* l) {
  __builtin_amdgcn_global_load_lds((__attribute__((address_space(1))) void*)g,
                                   (__attribute__((address_space(3))) void*)l,
                                   16, 0, 0);
}

__device__ __forceinline__ float slot_scale(const unsigned* slots, int idx) {
  // s = max(absmax/127, 1e-8), matching jnp.maximum(max/QMAX, 1e-8) in fp32
  return fmaxf(__uint_as_float(slots[idx]) / QMAXF, 1e-8f);
}

// ---------------- absmax reduction ------------------------------------------
__global__ void absmax_k(const float* __restrict__ in, int n4, unsigned* __restrict__ slot) {
  int tid = blockIdx.x * blockDim.x + threadIdx.x;
  int stride = gridDim.x * blockDim.x;
  float m = 0.f;
  const float4* in4 = (const float4*)in;
  for (int i = tid; i < n4; i += stride) {
    float4 v = in4[i];
    m = fmaxf(m, fmaxf(fmaxf(fabsf(v.x), fabsf(v.y)), fmaxf(fabsf(v.z), fabsf(v.w))));
  }
  #pragma unroll
  for (int off = 32; off; off >>= 1) m = fmaxf(m, __shfl_down(m, off));
  __shared__ float sm[4];
  int lane = threadIdx.x & 63, w = threadIdx.x >> 6;
  if (!lane) sm[w] = m;
  __syncthreads();
  if (!threadIdx.x) {
    m = fmaxf(fmaxf(sm[0], sm[1]), fmaxf(sm[2], sm[3]));
    atomicMax(slot, __float_as_uint(m));  // non-negative floats: uint order == float order
  }
}

// ---------------- quantize fp32 -> fp16 int grid, with zero padding ---------
// out has rows_out x cols_out (implied by total8*8); in is rows_in x cols_in.
__global__ void quant_k(const float* __restrict__ in, _Float16* __restrict__ out,
                        int rows_in, int cols_in, int cols_out, int total8,
                        const unsigned* __restrict__ slot) {
  float s = fmaxf(__uint_as_float(*slot) / QMAXF, 1e-8f);
  int t = blockIdx.x * blockDim.x + threadIdx.x;
  if (t >= total8) return;
  int idx = t * 8;
  int r = idx / cols_out;
  int c = idx - r * cols_out;
  half8 h;
  if (r < rows_in && c + 8 <= cols_in) {
    const float2* p = (const float2*)(in + (size_t)r * cols_in + c);
    #pragma unroll
    for (int j = 0; j < 4; ++j) {
      float2 v = p[j];
      float q0 = fminf(fmaxf(rintf(v.x / s), -QMAXF), QMAXF);
      float q1 = fminf(fmaxf(rintf(v.y / s), -QMAXF), QMAXF);
      h[2 * j]     = (_Float16)q0;
      h[2 * j + 1] = (_Float16)q1;
    }
  } else {
    #pragma unroll
    for (int j = 0; j < 8; ++j) {
      int cc = c + j;
      float v = 0.f;
      if (r < rows_in && cc < cols_in) v = in[(size_t)r * cols_in + cc];
      float q = fminf(fmaxf(rintf(v / s), -QMAXF), QMAXF);
      h[j] = (_Float16)q;
    }
  }
  *(half8*)(out + idx) = h;
}

// ---------------- activation: silu(fq(gate)) * fq(up) -----------------------
__device__ __forceinline__ float act_val(float g, float u, float sg, float su) {
  float gq = fminf(fmaxf(rintf(g / sg), -QMAXF), QMAXF) * sg;
  float uq = fminf(fmaxf(rintf(u / su), -QMAXF), QMAXF) * su;
  // jax.nn.sigmoid stable form
  float sig = (gq >= 0.f) ? (1.f / (1.f + expf(-gq)))
                          : (expf(gq) / (1.f + expf(gq)));
  return (gq * sig) * uq;
}

__global__ void act_max_k(const float* __restrict__ gate, const float* __restrict__ up,
                          const unsigned* __restrict__ slots, unsigned* __restrict__ outslot,
                          int n4) {
  float sg = slot_scale(slots, 4);
  float su = slot_scale(slots, 5);
  int tid = blockIdx.x * blockDim.x + threadIdx.x;
  int stride = gridDim.x * blockDim.x;
  float m = 0.f;
  const float4* g4 = (const float4*)gate;
  const float4* u4 = (const float4*)up;
  for (int i = tid; i < n4; i += stride) {
    float4 g = g4[i], u = u4[i];
    m = fmaxf(m, fabsf(act_val(g.x, u.x, sg, su)));
    m = fmaxf(m, fabsf(act_val(g.y, u.y, sg, su)));
    m = fmaxf(m, fabsf(act_val(g.z, u.z, sg, su)));
    m = fmaxf(m, fabsf(act_val(g.w, u.w, sg, su)));
  }
  #pragma unroll
  for (int off = 32; off; off >>= 1) m = fmaxf(m, __shfl_down(m, off));
  __shared__ float sm[4];
  int lane = threadIdx.x & 63, w = threadIdx.x >> 6;
  if (!lane) sm[w] = m;
  __syncthreads();
  if (!threadIdx.x) {
    m = fmaxf(fmaxf(sm[0], sm[1]), fmaxf(sm[2], sm[3]));
    atomicMax(outslot, __float_as_uint(m));
  }
}

__global__ void act_quant_k(const float* __restrict__ gate, const float* __restrict__ up,
                            const unsigned* __restrict__ slots, _Float16* __restrict__ actq,
                            int n4) {
  float sg = slot_scale(slots, 4);
  float su = slot_scale(slots, 5);
  float sa = slot_scale(slots, 6);
  int tid = blockIdx.x * blockDim.x + threadIdx.x;
  int stride = gridDim.x * blockDim.x;
  const float4* g4 = (const float4*)gate;
  const float4* u4 = (const float4*)up;
  for (int i = tid; i < n4; i += stride) {
    float4 g = g4[i], u = u4[i];
    float a0 = act_val(g.x, u.x, sg, su);
    float a1 = act_val(g.y, u.y, sg, su);
    float a2 = act_val(g.z, u.z, sg, su);
    float a3 = act_val(g.w, u.w, sg, su);
    half4v h;
    h[0] = (_Float16)fminf(fmaxf(rintf(a0 / sa), -QMAXF), QMAXF);
    h[1] = (_Float16)fminf(fmaxf(rintf(a1 / sa), -QMAXF), QMAXF);
    h[2] = (_Float16)fminf(fmaxf(rintf(a2 / sa), -QMAXF), QMAXF);
    h[3] = (_Float16)fminf(fmaxf(rintf(a3 / sa), -QMAXF), QMAXF);
    *(half4v*)(actq + (size_t)i * 4) = h;
  }
}

// ---------------- GEMM: C[m,n] = (sum_k A[m,k]*B[n,k]) * sA*sB + bias[n] ----
// A: M x K fp16 int-grid (lda), B: N x K fp16 int-grid (ldb), C fp32 (ldc).
// Tracks block absmax of C into maxslot. 128x128 tile, BK=32, 4 waves (2x2).
__global__ __launch_bounds__(256) void gemm_k(
    const _Float16* __restrict__ A, const _Float16* __restrict__ B,
    const float* __restrict__ bias, float* __restrict__ C,
    int K, int lda, int ldb, int ldc, int nbias,
    const unsigned* __restrict__ slots, int sa_idx, int sb_idx,
    unsigned* __restrict__ maxslot) {
  __shared__ __align__(16) _Float16 As[128 * 32];
  __shared__ __align__(16) _Float16 Bs[128 * 32];

  const int wave = threadIdx.x >> 6;
  const int lane = threadIdx.x & 63;
  const int wrow = wave >> 1, wcol = wave & 1;
  const int l16 = lane & 15, quad = lane >> 4;
  const int tm = blockIdx.x * 128, tn = blockIdx.y * 128;

  floatx4 acc[4][4] = {};

  const int so = wave * 2048 + lane * 16;  // byte offset into 8KB tile, pass 0
  const char* Ab = (const char*)A;
  const char* Bb = (const char*)B;

  for (int k0 = 0; k0 < K; k0 += 32) {
    #pragma unroll
    for (int p = 0; p < 2; ++p) {
      int bo = so + p * 1024;
      int row = bo >> 6;          // 64B per LDS row (32 fp16)
      int colb = bo & 63;
      gl_lds16(Ab + ((size_t)(tm + row) * lda + k0) * 2 + colb,
               (char*)As + wave * 2048 + p * 1024);
      gl_lds16(Bb + ((size_t)(tn + row) * ldb + k0) * 2 + colb,
               (char*)Bs + wave * 2048 + p * 1024);
    }
    __syncthreads();
    half8 af[4], bf[4];
    #pragma unroll
    for (int i = 0; i < 4; ++i) {
      af[i] = *(const half8*)((const char*)As + ((wrow * 64 + i * 16 + l16) * 64 + quad * 16));
      bf[i] = *(const half8*)((const char*)Bs + ((wcol * 64 + i * 16 + l16) * 64 + quad * 16));
    }
    #pragma unroll
    for (int i = 0; i < 4; ++i)
      #pragma unroll
      for (int j = 0; j < 4; ++j)
        acc[i][j] = __builtin_amdgcn_mfma_f32_16x16x32_f16(af[i], bf[j], acc[i][j], 0, 0, 0);
    __syncthreads();
  }

  float scale = slot_scale(slots, sa_idx) * slot_scale(slots, sb_idx);
  float mloc = 0.f;
  #pragma unroll
  for (int i = 0; i < 4; ++i) {
    int rg0 = tm + wrow * 64 + i * 16 + quad * 4;
    #pragma unroll
    for (int j = 0; j < 4; ++j) {
      int cg = tn + wcol * 64 + j * 16 + l16;
      float bv = (cg < nbias) ? bias[cg] : 0.f;  // padded cols: acc==0, bv==0 -> exact 0
      #pragma unroll
      for (int r = 0; r < 4; ++r) {
        float v = acc[i][j][r] * scale + bv;
        C[(size_t)(rg0 + r) * ldc + cg] = v;
        mloc = fmaxf(mloc, fabsf(v));
      }
    }
  }
  #pragma unroll
  for (int off = 32; off; off >>= 1) mloc = fmaxf(mloc, __shfl_down(mloc, off));
  __shared__ float smx[4];
  if (!lane) smx[wave] = mloc;
  __syncthreads();
  if (!threadIdx.x)
    atomicMax(maxslot, __float_as_uint(fmaxf(fmaxf(smx[0], smx[1]), fmaxf(smx[2], smx[3]))));
}

// ---------------- host-side orchestration -----------------------------------
extern "C" void kernel_launch(void* const* d_in, const int* in_sizes, int n_in,
                              void* d_out, int out_size, void* d_ws, size_t ws_size,
                              hipStream_t stream) {
  const float* x  = (const float*)d_in[0];
  const float* wg = (const float*)d_in[1];
  const float* wu = (const float*)d_in[2];
  const float* wd = (const float*)d_in[3];
  const float* bg = (const float*)d_in[4];
  const float* bu = (const float*)d_in[5];
  const float* bd = (const float*)d_in[6];
  float* out = (float*)d_out;

  char* ws = (char*)d_ws;
  unsigned* slots = (unsigned*)ws;
  // slots: 0:max|x| 1:max|wg| 2:max|wu| 3:max|wd| 4:max|gate| 5:max|up| 6:max|act| 7:dummy
  const size_t XQ_B = (size_t)MTOK * D_MODEL * 2;   // 33,554,432
  const size_t WQ_B = (size_t)HIDP * D_MODEL * 2;   // 90,177,536
  const size_t GU_B = (size_t)MTOK * HIDP * 4;      // 180,355,072

  _Float16* xq   = (_Float16*)(ws + 256);
  _Float16* wgq  = (_Float16*)(ws + 256 + XQ_B);
  _Float16* wuq  = (_Float16*)(ws + 256 + XQ_B + WQ_B);
  float*    gate = (float*)   (ws + 256 + XQ_B + 2 * WQ_B);
  float*    up   = (float*)   (ws + 256 + XQ_B + 2 * WQ_B + GU_B);
  // reuse dead regions after GEMM1:
  _Float16* actq = wgq;                              // 4096*11008*2 == WQ_B
  _Float16* wdq  = wuq;                              // 4096*11008*2 == WQ_B

  hipMemsetAsync(ws, 0, 256, stream);  // zero the max slots

  // 1) absmax of inputs
  absmax_k<<<2048, 256, 0, stream>>>(x,  MTOK * D_MODEL / 4, slots + 0);
  absmax_k<<<2048, 256, 0, stream>>>(wg, HID * D_MODEL / 4,  slots + 1);
  absmax_k<<<2048, 256, 0, stream>>>(wu, HID * D_MODEL / 4,  slots + 2);
  absmax_k<<<2048, 256, 0, stream>>>(wd, MTOK * HID / 4,     slots + 3);

  // 2) quantize x, wg, wu to fp16 int grid (weights padded to HIDP rows)
  {
    int t8 = MTOK * D_MODEL / 8;
    quant_k<<<(t8 + 255) / 256, 256, 0, stream>>>(x, xq, MTOK, D_MODEL, D_MODEL, t8, slots + 0);
    int w8 = HIDP * D_MODEL / 8;
    quant_k<<<(w8 + 255) / 256, 256, 0, stream>>>(wg, wgq, HID, D_MODEL, D_MODEL, w8, slots + 1);
    quant_k<<<(w8 + 255) / 256, 256, 0, stream>>>(wu, wuq, HID, D_MODEL, D_MODEL, w8, slots + 2);
  }

  // 3) GEMM1: gate & up (fp32, scale+bias fused, absmax tracked)
  {
    dim3 g1(MTOK / 128, HIDP / 128);
    gemm_k<<<g1, 256, 0, stream>>>(xq, wgq, bg, gate, D_MODEL, D_MODEL, D_MODEL, HIDP, HID,
                                   slots, 0, 1, slots + 4);
    gemm_k<<<g1, 256, 0, stream>>>(xq, wuq, bu, up,   D_MODEL, D_MODEL, D_MODEL, HIDP, HID,
                                   slots, 0, 2, slots + 5);
  }

  // 4) quantize wd into wuq region (cols padded to HIDP)
  {
    int t8 = MTOK * HIDP / 8;
    quant_k<<<(t8 + 255) / 256, 256, 0, stream>>>(wd, wdq, MTOK, HID, HIDP, t8, slots + 3);
  }

  // 5) activation: pass 1 (absmax), pass 2 (quantize into wgq region)
  {
    int n4 = MTOK * HIDP / 4;
    act_max_k<<<4096, 256, 0, stream>>>(gate, up, slots, slots + 6, n4);
    act_quant_k<<<4096, 256, 0, stream>>>(gate, up, slots, actq, n4);
  }

  // 6) GEMM2: out = actq . wdq^T * (sa*swd) + bd
  {
    dim3 g2(MTOK / 128, D_MODEL / 128);
    gemm_k<<<g2, 256, 0, stream>>>(actq, wdq, bd, out, HIDP, HIDP, HIDP, D_MODEL, D_MODEL,
                                   slots, 6, 3, slots + 7);
  }
}

// Round 2
// 2493.842 us; speedup vs baseline: 1.0280x; 1.0280x over previous
//
#include <hip/hip_runtime.h>

#define D_MODEL 4096
#define HID     10922
#define HIDP    11008   // padded to multiple of 128
#define MTOK    4096
#define QMAXF   127.0f

typedef _Float16 half8  __attribute__((ext_vector_type(8)));
typedef _Float16 half4v __attribute__((ext_vector_type(4)));
typedef float    floatx4 __attribute__((ext_vector_type(4)));

// ---------------- async global->LDS (16B per lane, wave-uniform LDS base) ----
__device__ __forceinline__ void gl_lds16(const void* g, void* l) {
  __builtin_amdgcn_global_load_lds((__attribute__((address_space(1))) void*)g,
                                   (__attribute__((address_space(3))) void*)l,
                                   16, 0, 0);
}

__device__ __forceinline__ float slot_scale(const unsigned* slots, int idx) {
  // s = max(absmax/127, 1e-8), matching jnp.maximum(max/QMAX, 1e-8) in fp32
  return fmaxf(__uint_as_float(slots[idx]) / QMAXF, 1e-8f);
}

// ---------------- absmax reduction ------------------------------------------
__global__ void absmax_k(const float* __restrict__ in, int n4, unsigned* __restrict__ slot) {
  int tid = blockIdx.x * blockDim.x + threadIdx.x;
  int stride = gridDim.x * blockDim.x;
  float m = 0.f;
  const float4* in4 = (const float4*)in;
  for (int i = tid; i < n4; i += stride) {
    float4 v = in4[i];
    m = fmaxf(m, fmaxf(fmaxf(fabsf(v.x), fabsf(v.y)), fmaxf(fabsf(v.z), fabsf(v.w))));
  }
  #pragma unroll
  for (int off = 32; off; off >>= 1) m = fmaxf(m, __shfl_down(m, off));
  __shared__ float sm[4];
  int lane = threadIdx.x & 63, w = threadIdx.x >> 6;
  if (!lane) sm[w] = m;
  __syncthreads();
  if (!threadIdx.x) {
    m = fmaxf(fmaxf(sm[0], sm[1]), fmaxf(sm[2], sm[3]));
    atomicMax(slot, __float_as_uint(m));  // non-negative floats: uint order == float order
  }
}

// ---------------- quantize fp32 -> fp16 int grid, with zero padding ---------
__global__ void quant_k(const float* __restrict__ in, _Float16* __restrict__ out,
                        int rows_in, int cols_in, int cols_out, int total8,
                        const unsigned* __restrict__ slot) {
  float s = fmaxf(__uint_as_float(*slot) / QMAXF, 1e-8f);
  int t = blockIdx.x * blockDim.x + threadIdx.x;
  if (t >= total8) return;
  int idx = t * 8;
  int r = idx / cols_out;
  int c = idx - r * cols_out;
  half8 h;
  if (r < rows_in && c + 8 <= cols_in) {
    const float2* p = (const float2*)(in + (size_t)r * cols_in + c);
    #pragma unroll
    for (int j = 0; j < 4; ++j) {
      float2 v = p[j];
      float q0 = fminf(fmaxf(rintf(v.x / s), -QMAXF), QMAXF);
      float q1 = fminf(fmaxf(rintf(v.y / s), -QMAXF), QMAXF);
      h[2 * j]     = (_Float16)q0;
      h[2 * j + 1] = (_Float16)q1;
    }
  } else {
    #pragma unroll
    for (int j = 0; j < 8; ++j) {
      int cc = c + j;
      float v = 0.f;
      if (r < rows_in && cc < cols_in) v = in[(size_t)r * cols_in + cc];
      float q = fminf(fmaxf(rintf(v / s), -QMAXF), QMAXF);
      h[j] = (_Float16)q;
    }
  }
  *(half8*)(out + idx) = h;
}

// ---------------- activation: silu(fq(gate)) * fq(up) -----------------------
__device__ __forceinline__ float act_val(float g, float u, float sg, float su) {
  float gq = fminf(fmaxf(rintf(g / sg), -QMAXF), QMAXF) * sg;
  float uq = fminf(fmaxf(rintf(u / su), -QMAXF), QMAXF) * su;
  float sig = (gq >= 0.f) ? (1.f / (1.f + expf(-gq)))
                          : (expf(gq) / (1.f + expf(gq)));
  return (gq * sig) * uq;
}

__global__ void act_max_k(const float* __restrict__ gate, const float* __restrict__ up,
                          const unsigned* __restrict__ slots, unsigned* __restrict__ outslot,
                          int n4) {
  float sg = slot_scale(slots, 4);
  float su = slot_scale(slots, 5);
  int tid = blockIdx.x * blockDim.x + threadIdx.x;
  int stride = gridDim.x * blockDim.x;
  float m = 0.f;
  const float4* g4 = (const float4*)gate;
  const float4* u4 = (const float4*)up;
  for (int i = tid; i < n4; i += stride) {
    float4 g = g4[i], u = u4[i];
    m = fmaxf(m, fabsf(act_val(g.x, u.x, sg, su)));
    m = fmaxf(m, fabsf(act_val(g.y, u.y, sg, su)));
    m = fmaxf(m, fabsf(act_val(g.z, u.z, sg, su)));
    m = fmaxf(m, fabsf(act_val(g.w, u.w, sg, su)));
  }
  #pragma unroll
  for (int off = 32; off; off >>= 1) m = fmaxf(m, __shfl_down(m, off));
  __shared__ float sm[4];
  int lane = threadIdx.x & 63, w = threadIdx.x >> 6;
  if (!lane) sm[w] = m;
  __syncthreads();
  if (!threadIdx.x) {
    m = fmaxf(fmaxf(sm[0], sm[1]), fmaxf(sm[2], sm[3]));
    atomicMax(outslot, __float_as_uint(m));
  }
}

__global__ void act_quant_k(const float* __restrict__ gate, const float* __restrict__ up,
                            const unsigned* __restrict__ slots, _Float16* __restrict__ actq,
                            int n4) {
  float sg = slot_scale(slots, 4);
  float su = slot_scale(slots, 5);
  float sa = slot_scale(slots, 6);
  int tid = blockIdx.x * blockDim.x + threadIdx.x;
  int stride = gridDim.x * blockDim.x;
  const float4* g4 = (const float4*)gate;
  const float4* u4 = (const float4*)up;
  for (int i = tid; i < n4; i += stride) {
    float4 g = g4[i], u = u4[i];
    float a0 = act_val(g.x, u.x, sg, su);
    float a1 = act_val(g.y, u.y, sg, su);
    float a2 = act_val(g.z, u.z, sg, su);
    float a3 = act_val(g.w, u.w, sg, su);
    half4v h;
    h[0] = (_Float16)fminf(fmaxf(rintf(a0 / sa), -QMAXF), QMAXF);
    h[1] = (_Float16)fminf(fmaxf(rintf(a1 / sa), -QMAXF), QMAXF);
    h[2] = (_Float16)fminf(fmaxf(rintf(a2 / sa), -QMAXF), QMAXF);
    h[3] = (_Float16)fminf(fmaxf(rintf(a3 / sa), -QMAXF), QMAXF);
    *(half4v*)(actq + (size_t)i * 4) = h;
  }
}

// ---------------- GEMM: C[m,n] = (sum_k A[m,k]*B[n,k]) * sA*sB + bias[n] ----
// 128x128 tile, BK=32, 4 waves (2x2 of 64x64). LDS rows are 64 B (32 fp16),
// split into 4 chunks of 16 B. Chunk index is XOR-swizzled with (row>>1)&3 so
// fragment ds_read_b128 hits all 8 bank-groups 2x per quarter-wave (2-way is
// free — m136); the inverse permutation is applied to the global source
// address at staging time (stays 64B-coalesced; global_load_lds dest must
// remain contiguous, so padding is not an option).
__global__ __launch_bounds__(256) void gemm_k(
    const _Float16* __restrict__ A, const _Float16* __restrict__ B,
    const float* __restrict__ bias, float* __restrict__ C,
    int K, int lda, int ldb, int ldc, int nbias,
    const unsigned* __restrict__ slots, int sa_idx, int sb_idx,
    unsigned* __restrict__ maxslot) {
  __shared__ __align__(16) _Float16 As[128 * 32];
  __shared__ __align__(16) _Float16 Bs[128 * 32];

  const int wave = threadIdx.x >> 6;
  const int lane = threadIdx.x & 63;
  const int wrow = wave >> 1, wcol = wave & 1;
  const int l16 = lane & 15, quad = lane >> 4;
  const int tm = blockIdx.x * 128, tn = blockIdx.y * 128;

  floatx4 acc[4][4] = {};

  const int so = wave * 2048 + lane * 16;  // byte offset into 8KB tile, pass 0
  const char* Ab = (const char*)A;
  const char* Bb = (const char*)B;

  for (int k0 = 0; k0 < K; k0 += 32) {
    #pragma unroll
    for (int p = 0; p < 2; ++p) {
      int bo = so + p * 1024;
      int row = bo >> 6;                       // tile row (64 B per LDS row)
      int csrc = ((bo >> 4) & 3) ^ ((row >> 1) & 3);  // swizzled source chunk
      gl_lds16(Ab + ((size_t)(tm + row) * lda + k0) * 2 + csrc * 16,
               (char*)As + wave * 2048 + p * 1024);
      gl_lds16(Bb + ((size_t)(tn + row) * ldb + k0) * 2 + csrc * 16,
               (char*)Bs + wave * 2048 + p * 1024);
    }
    __syncthreads();
    half8 af[4], bf[4];
    #pragma unroll
    for (int i = 0; i < 4; ++i) {
      int ra = wrow * 64 + i * 16 + l16;
      int rb = wcol * 64 + i * 16 + l16;
      af[i] = *(const half8*)((const char*)As + (ra * 64 + (quad ^ ((ra >> 1) & 3)) * 16));
      bf[i] = *(const half8*)((const char*)Bs + (rb * 64 + (quad ^ ((rb >> 1) & 3)) * 16));
    }
    #pragma unroll
    for (int i = 0; i < 4; ++i)
      #pragma unroll
      for (int j = 0; j < 4; ++j)
        acc[i][j] = __builtin_amdgcn_mfma_f32_16x16x32_f16(af[i], bf[j], acc[i][j], 0, 0, 0);
    __syncthreads();
  }

  float scale = slot_scale(slots, sa_idx) * slot_scale(slots, sb_idx);
  float mloc = 0.f;
  #pragma unroll
  for (int i = 0; i < 4; ++i) {
    int rg0 = tm + wrow * 64 + i * 16 + quad * 4;
    #pragma unroll
    for (int j = 0; j < 4; ++j) {
      int cg = tn + wcol * 64 + j * 16 + l16;
      float bv = (cg < nbias) ? bias[cg] : 0.f;  // padded cols: acc==0, bv==0 -> exact 0
      #pragma unroll
      for (int r = 0; r < 4; ++r) {
        float v = acc[i][j][r] * scale + bv;
        C[(size_t)(rg0 + r) * ldc + cg] = v;
        mloc = fmaxf(mloc, fabsf(v));
      }
    }
  }
  #pragma unroll
  for (int off = 32; off; off >>= 1) mloc = fmaxf(mloc, __shfl_down(mloc, off));
  __shared__ float smx[4];
  if (!lane) smx[wave] = mloc;
  __syncthreads();
  if (!threadIdx.x)
    atomicMax(maxslot, __float_as_uint(fmaxf(fmaxf(smx[0], smx[1]), fmaxf(smx[2], smx[3]))));
}

// ---------------- host-side orchestration -----------------------------------
extern "C" void kernel_launch(void* const* d_in, const int* in_sizes, int n_in,
                              void* d_out, int out_size, void* d_ws, size_t ws_size,
                              hipStream_t stream) {
  const float* x  = (const float*)d_in[0];
  const float* wg = (const float*)d_in[1];
  const float* wu = (const float*)d_in[2];
  const float* wd = (const float*)d_in[3];
  const float* bg = (const float*)d_in[4];
  const float* bu = (const float*)d_in[5];
  const float* bd = (const float*)d_in[6];
  float* out = (float*)d_out;

  char* ws = (char*)d_ws;
  unsigned* slots = (unsigned*)ws;
  // slots: 0:max|x| 1:max|wg| 2:max|wu| 3:max|wd| 4:max|gate| 5:max|up| 6:max|act| 7:dummy
  const size_t XQ_B = (size_t)MTOK * D_MODEL * 2;   // 33,554,432
  const size_t WQ_B = (size_t)HIDP * D_MODEL * 2;   // 90,177,536
  const size_t GU_B = (size_t)MTOK * HIDP * 4;      // 180,355,072

  _Float16* xq   = (_Float16*)(ws + 256);
  _Float16* wgq  = (_Float16*)(ws + 256 + XQ_B);
  _Float16* wuq  = (_Float16*)(ws + 256 + XQ_B + WQ_B);
  float*    gate = (float*)   (ws + 256 + XQ_B + 2 * WQ_B);
  float*    up   = (float*)   (ws + 256 + XQ_B + 2 * WQ_B + GU_B);
  // reuse dead regions after GEMM1:
  _Float16* actq = wgq;                              // 4096*11008*2 == WQ_B
  _Float16* wdq  = wuq;                              // 4096*11008*2 == WQ_B

  hipMemsetAsync(ws, 0, 256, stream);  // zero the max slots

  // 1) absmax of inputs
  absmax_k<<<2048, 256, 0, stream>>>(x,  MTOK * D_MODEL / 4, slots + 0);
  absmax_k<<<2048, 256, 0, stream>>>(wg, HID * D_MODEL / 4,  slots + 1);
  absmax_k<<<2048, 256, 0, stream>>>(wu, HID * D_MODEL / 4,  slots + 2);
  absmax_k<<<2048, 256, 0, stream>>>(wd, MTOK * HID / 4,     slots + 3);

  // 2) quantize x, wg, wu to fp16 int grid (weights padded to HIDP rows)
  {
    int t8 = MTOK * D_MODEL / 8;
    quant_k<<<(t8 + 255) / 256, 256, 0, stream>>>(x, xq, MTOK, D_MODEL, D_MODEL, t8, slots + 0);
    int w8 = HIDP * D_MODEL / 8;
    quant_k<<<(w8 + 255) / 256, 256, 0, stream>>>(wg, wgq, HID, D_MODEL, D_MODEL, w8, slots + 1);
    quant_k<<<(w8 + 255) / 256, 256, 0, stream>>>(wu, wuq, HID, D_MODEL, D_MODEL, w8, slots + 2);
  }

  // 3) GEMM1: gate & up (fp32, scale+bias fused, absmax tracked)
  {
    dim3 g1(MTOK / 128, HIDP / 128);
    gemm_k<<<g1, 256, 0, stream>>>(xq, wgq, bg, gate, D_MODEL, D_MODEL, D_MODEL, HIDP, HID,
                                   slots, 0, 1, slots + 4);
    gemm_k<<<g1, 256, 0, stream>>>(xq, wuq, bu, up,   D_MODEL, D_MODEL, D_MODEL, HIDP, HID,
                                   slots, 0, 2, slots + 5);
  }

  // 4) quantize wd into wuq region (cols padded to HIDP)
  {
    int t8 = MTOK * HIDP / 8;
    quant_k<<<(t8 + 255) / 256, 256, 0, stream>>>(wd, wdq, MTOK, HID, HIDP, t8, slots + 3);
  }

  // 5) activation: pass 1 (absmax), pass 2 (quantize into wgq region)
  {
    int n4 = MTOK * HIDP / 4;
    act_max_k<<<4096, 256, 0, stream>>>(gate, up, slots, slots + 6, n4);
    act_quant_k<<<4096, 256, 0, stream>>>(gate, up, slots, actq, n4);
  }

  // 6) GEMM2: out = actq . wdq^T * (sa*swd) + bd
  {
    dim3 g2(MTOK / 128, D_MODEL / 128);
    gemm_k<<<g2, 256, 0, stream>>>(actq, wdq, bd, out, HIDP, HIDP, HIDP, D_MODEL, D_MODEL,
                                   slots, 6, 3, slots + 7);
  }
}